// Round 1
// baseline (200.547 us; speedup 1.0000x reference)
//
#include <hip/hip_runtime.h>
#include <cstdint>

#define BB 32
#define PP 131072
#define NEG_RATIO 3

// Workspace accumulators (zeroed via hipMemsetAsync each launch).
struct Ws {
  double sum_sl1;            // global sum of smoothL1 * pos
  double sum_ce_all[BB];     // per-batch sum of CE over all priors
  double sum_ce_pos[BB];     // per-batch sum of CE over positives
  double ce_neg[BB];         // per-batch CE sum over selected negatives (case-2 only)
  int    num_pos[BB];
};

__device__ __forceinline__ float sl1f(float a, float b) {
  float d = fabsf(a - b);
  return d < 1.0f ? 0.5f * d * d : d - 0.5f;
}

// ce = logsumexp(c0,c1) - c[t]; score = pos ? 0 : ce  (score >= 0 always)
__device__ __forceinline__ float ce_of(float c0, float c1, int t) {
  float m = fmaxf(c0, c1), mn = fminf(c0, c1);
  float lse = m + log1pf(expf(mn - m));
  return lse - (t ? c1 : c0);
}

// ---------------- K1: fused elementwise + reductions ----------------
// 8 priors/thread, 256 threads/block -> 2048 priors/block, 2048 blocks.
// Each block is entirely within one batch (2048 | 131072).
__global__ __launch_bounds__(256) void k_main(
    const float4* __restrict__ loc, const float2* __restrict__ conf,
    const float4* __restrict__ loct, const int* __restrict__ conft,
    Ws* __restrict__ ws) {
  const int tid = threadIdx.x;
  const int base = blockIdx.x * 2048;
  const int batch = base >> 17;  // /131072

  double a_sl1 = 0.0, a_ce_all = 0.0, a_ce_pos = 0.0;
  int a_np = 0;

#pragma unroll
  for (int k = 0; k < 8; ++k) {
    const int i = base + k * 256 + tid;
    const float4 l  = loc[i];
    const float4 lt = loct[i];
    const float2 c  = conf[i];
    const int    t  = conft[i];
    const bool pos = t > 0;

    const float ce = ce_of(c.x, c.y, t);
    a_ce_all += (double)ce;

    const float s = sl1f(l.x, lt.x) + sl1f(l.y, lt.y) +
                    sl1f(l.z, lt.z) + sl1f(l.w, lt.w);
    if (pos) {
      a_ce_pos += (double)ce;
      a_sl1    += (double)s;
      a_np     += 1;
    }
  }

  // wave (64-lane) reduction
#pragma unroll
  for (int off = 32; off; off >>= 1) {
    a_sl1    += __shfl_down(a_sl1, off);
    a_ce_all += __shfl_down(a_ce_all, off);
    a_ce_pos += __shfl_down(a_ce_pos, off);
    a_np     += __shfl_down(a_np, off);
  }

  __shared__ double s1[4], s2[4], s3[4];
  __shared__ int s4[4];
  const int wave = tid >> 6, lane = tid & 63;
  if (lane == 0) { s1[wave] = a_sl1; s2[wave] = a_ce_all; s3[wave] = a_ce_pos; s4[wave] = a_np; }
  __syncthreads();
  if (tid == 0) {
    atomicAdd(&ws->sum_sl1,           s1[0] + s1[1] + s1[2] + s1[3]);
    atomicAdd(&ws->sum_ce_all[batch], s2[0] + s2[1] + s2[2] + s2[3]);
    atomicAdd(&ws->sum_ce_pos[batch], s3[0] + s3[1] + s3[2] + s3[3]);
    atomicAdd(&ws->num_pos[batch],    s4[0] + s4[1] + s4[2] + s4[3]);
  }
}

// ---------------- K2: general top-k negative selection (case 2) ----------------
// Only runs for batches where num_neg < (P - num_pos). For the bench data this
// never triggers (num_neg = P-1 >= M), so the block exits immediately.
// Radix select over fp32 score bits (score>=0 -> uint order == float order),
// 3 LDS-histogram passes (11/11/10 bits), then a stable index-ordered tie scan.
__global__ __launch_bounds__(256) void k_select(
    const float2* __restrict__ conf, const int* __restrict__ conft,
    Ws* __restrict__ ws) {
  const int b = blockIdx.x;
  const int npos = ws->num_pos[b];
  const long long M = (long long)PP - npos;
  long long k = (long long)NEG_RATIO * npos;
  if (k > PP - 1) k = PP - 1;
  if (k >= M) return;   // case 1: sel == everything, finalize handles it
  if (k <= 0) return;   // no negatives selected

  const int tid = threadIdx.x;
  const int rowbase = b * PP;

  __shared__ unsigned hist[2048];
  __shared__ unsigned sh_prefix;
  __shared__ long long sh_kk;

  unsigned prefix = 0;
  long long kk = k;
  const int shifts[3] = {21, 10, 0};
  const int widths[3] = {11, 11, 10};

  for (int pass = 0; pass < 3; ++pass) {
    const int shift = shifts[pass], width = widths[pass];
    const unsigned mask = (1u << width) - 1u;
    for (int j = tid; j < 2048; j += 256) hist[j] = 0;
    __syncthreads();
    for (int i = tid; i < PP; i += 256) {
      const float2 c = conf[rowbase + i];
      const int t = conft[rowbase + i];
      const float score = (t > 0) ? 0.0f : ce_of(c.x, c.y, t);
      const unsigned u = __float_as_uint(score);
      const bool match = (pass == 0) || ((u >> (shift + width)) == prefix);
      if (match) atomicAdd(&hist[(u >> shift) & mask], 1u);
    }
    __syncthreads();
    if (tid == 0) {
      long long c = 0;
      int d = (int)mask;
      for (; d >= 0; --d) {
        c += hist[d];
        if (c >= kk) break;
      }
      if (d < 0) d = 0;  // safety; invariant guarantees break
      sh_prefix = (prefix << width) | (unsigned)d;
      sh_kk = kk - (c - (long long)hist[d]);
    }
    __syncthreads();
    prefix = sh_prefix;
    kk = sh_kk;
    __syncthreads();
  }

  // prefix == T bits (k-th largest score, > 0 since k < M). kk = #ties to
  // include, taken in ascending index order (stable argsort semantics).
  const unsigned Tbits = prefix;
  double local_ce = 0.0;
  __shared__ unsigned wavecnt[4];
  __shared__ long long s_rt;
  if (tid == 0) s_rt = 0;
  __syncthreads();
  const int lane = tid & 63, wave = tid >> 6;

  for (int basei = 0; basei < PP; basei += 256) {
    const int i = basei + tid;
    const float2 c = conf[rowbase + i];
    const int t = conft[rowbase + i];
    const float ce = ce_of(c.x, c.y, t);
    const float score = (t > 0) ? 0.0f : ce;
    const unsigned u = __float_as_uint(score);
    const bool gt = u > Tbits;
    const bool eq = (u == Tbits);
    const unsigned long long bal = __ballot(eq ? 1 : 0);
    if (lane == 0) wavecnt[wave] = (unsigned)__popcll(bal);
    __syncthreads();
    long long cross = s_rt;
    for (int w = 0; w < wave; ++w) cross += wavecnt[w];
    const long long myord = cross + __popcll(bal & ((1ULL << lane) - 1ULL));
    if (gt || (eq && myord < kk)) local_ce += (double)ce;
    __syncthreads();
    if (tid == 0) s_rt += (long long)wavecnt[0] + wavecnt[1] + wavecnt[2] + wavecnt[3];
    __syncthreads();
  }

#pragma unroll
  for (int off = 32; off; off >>= 1) local_ce += __shfl_down(local_ce, off);
  __shared__ double s_ce[4];
  if (lane == 0) s_ce[wave] = local_ce;
  __syncthreads();
  if (tid == 0) ws->ce_neg[b] = s_ce[0] + s_ce[1] + s_ce[2] + s_ce[3];
}

// ---------------- K3: finalize ----------------
__global__ __launch_bounds__(64) void k_final(const Ws* __restrict__ ws,
                                              float* __restrict__ out) {
  const int tid = threadIdx.x;
  double np_d = 0.0, ce_sel = 0.0, cnt = 0.0;
  if (tid < BB) {
    const int npos = ws->num_pos[tid];
    const long long M = (long long)PP - npos;
    long long k = (long long)NEG_RATIO * npos;
    if (k > PP - 1) k = PP - 1;
    np_d = (double)npos;
    if (k >= M) {  // case 1: sel covers every prior
      ce_sel = ws->sum_ce_all[tid];
      cnt = (double)PP;
    } else {
      const long long kc = k > 0 ? k : 0;
      ce_sel = ws->sum_ce_pos[tid] + ws->ce_neg[tid];
      cnt = (double)(npos + kc);
    }
  }
#pragma unroll
  for (int off = 32; off; off >>= 1) {
    np_d   += __shfl_down(np_d, off);
    ce_sel += __shfl_down(ce_sel, off);
    cnt    += __shfl_down(cnt, off);
  }
  if (tid == 0) {
    const double N = np_d;
    const double S = ws->sum_sl1;
    out[0] = (float)(S / (4.0 * N * N));
    out[1] = (float)(ce_sel / cnt / N);
  }
}

extern "C" void kernel_launch(void* const* d_in, const int* in_sizes, int n_in,
                              void* d_out, int out_size, void* d_ws, size_t ws_size,
                              hipStream_t stream) {
  const float4* loc  = (const float4*)d_in[0];
  const float2* conf = (const float2*)d_in[1];
  const float4* loct = (const float4*)d_in[2];
  const int*    cnft = (const int*)d_in[3];
  Ws* ws = (Ws*)d_ws;

  hipMemsetAsync(d_ws, 0, sizeof(Ws), stream);
  k_main<<<dim3((BB * PP) / 2048), dim3(256), 0, stream>>>(loc, conf, loct, cnft, ws);
  k_select<<<dim3(BB), dim3(256), 0, stream>>>(conf, cnft, ws);
  k_final<<<dim3(1), dim3(64), 0, stream>>>(ws, (float*)d_out);
}

// Round 2
// 194.597 us; speedup vs baseline: 1.0306x; 1.0306x over previous
//
#include <hip/hip_runtime.h>
#include <cstdint>

#define BB 32
#define PP 131072
#define NEG_RATIO 3

// Workspace accumulators (zeroed via hipMemsetAsync each launch).
// fp32 partial sums: relative error ~1e-6 against a 2.5%-relative threshold.
struct Ws {
  float sum_sl1[BB];     // per-batch sum of smoothL1 * pos
  float sum_ce_all[BB];  // per-batch sum of CE over all priors
  float sum_ce_pos[BB];  // per-batch sum of CE over positives
  float ce_neg[BB];      // per-batch CE sum over selected negatives (case-2 only)
  int   num_pos[BB];
};

__device__ __forceinline__ float sl1sum(float4 a, float4 b) {
  float dx = fabsf(a.x - b.x), dy = fabsf(a.y - b.y),
        dz = fabsf(a.z - b.z), dw = fabsf(a.w - b.w);
  float sx = dx < 1.0f ? 0.5f * dx * dx : dx - 0.5f;
  float sy = dy < 1.0f ? 0.5f * dy * dy : dy - 0.5f;
  float sz = dz < 1.0f ? 0.5f * dz * dz : dz - 0.5f;
  float sw = dw < 1.0f ? 0.5f * dw * dw : dw - 0.5f;
  return (sx + sy) + (sz + sw);
}

// ce = logsumexp(c0,c1) - c[t]  (>= 0 when t picks the smaller logit; always >= 0 as used)
__device__ __forceinline__ float ce_fast(float c0, float c1, int t) {
  float m = fmaxf(c0, c1);
  float d = fabsf(c0 - c1);
  float lse = m + __logf(1.0f + __expf(-d));
  return lse - (t ? c1 : c0);
}

// exact-ish version for the (never-taken on bench data) select path
__device__ __forceinline__ float ce_of(float c0, float c1, int t) {
  float m = fmaxf(c0, c1), mn = fminf(c0, c1);
  float lse = m + log1pf(expf(mn - m));
  return lse - (t ? c1 : c0);
}

// ---------------- K1: fused elementwise + reductions ----------------
// 4 consecutive priors per thread; 11 independent dwordx4-class loads issued
// up front (4 loc + 4 loct + 2 conf + 1 conft) for memory-level parallelism.
// Block covers 1024 priors -> 128 blocks per batch, 4096 blocks total.
__global__ __launch_bounds__(256) void k_main(
    const float4* __restrict__ loc, const float4* __restrict__ conf2,
    const float4* __restrict__ loct, const int4* __restrict__ conft4,
    Ws* __restrict__ ws) {
  const int gtid = blockIdx.x * 256 + threadIdx.x;  // handles priors [4g, 4g+4)
  const int batch = blockIdx.x >> 7;                // 131072/1024 = 128 blocks/batch
  const int p0 = gtid * 4;

  // ---- issue all loads first (no dependences between them) ----
  const float4 l0 = loc[p0 + 0], l1 = loc[p0 + 1], l2 = loc[p0 + 2], l3 = loc[p0 + 3];
  const float4 t0 = loct[p0 + 0], t1 = loct[p0 + 1], t2 = loct[p0 + 2], t3 = loct[p0 + 3];
  const float4 ca = conf2[gtid * 2 + 0];  // priors 4g, 4g+1 : (c0,c1,c0,c1)
  const float4 cb = conf2[gtid * 2 + 1];  // priors 4g+2, 4g+3
  const int4   tt = conft4[gtid];

  // ---- compute ----
  const float ce0 = ce_fast(ca.x, ca.y, tt.x);
  const float ce1 = ce_fast(ca.z, ca.w, tt.y);
  const float ce2 = ce_fast(cb.x, cb.y, tt.z);
  const float ce3 = ce_fast(cb.z, cb.w, tt.w);

  const float s0 = sl1sum(l0, t0), s1 = sl1sum(l1, t1),
              s2 = sl1sum(l2, t2), s3 = sl1sum(l3, t3);

  const float m0 = tt.x > 0 ? 1.0f : 0.0f, m1 = tt.y > 0 ? 1.0f : 0.0f,
              m2 = tt.z > 0 ? 1.0f : 0.0f, m3 = tt.w > 0 ? 1.0f : 0.0f;

  float a_ce_all = (ce0 + ce1) + (ce2 + ce3);
  float a_ce_pos = (m0 * ce0 + m1 * ce1) + (m2 * ce2 + m3 * ce3);
  float a_sl1    = (m0 * s0 + m1 * s1) + (m2 * s2 + m3 * s3);
  int   a_np     = (tt.x > 0) + (tt.y > 0) + (tt.z > 0) + (tt.w > 0);

  // ---- wave (64-lane) reduction ----
#pragma unroll
  for (int off = 32; off; off >>= 1) {
    a_sl1    += __shfl_down(a_sl1, off);
    a_ce_all += __shfl_down(a_ce_all, off);
    a_ce_pos += __shfl_down(a_ce_pos, off);
    a_np     += __shfl_down(a_np, off);
  }

  __shared__ float s1s[4], s2s[4], s3s[4];
  __shared__ int s4s[4];
  const int wave = threadIdx.x >> 6, lane = threadIdx.x & 63;
  if (lane == 0) { s1s[wave] = a_sl1; s2s[wave] = a_ce_all; s3s[wave] = a_ce_pos; s4s[wave] = a_np; }
  __syncthreads();
  if (threadIdx.x == 0) {
    atomicAdd(&ws->sum_sl1[batch],    (s1s[0] + s1s[1]) + (s1s[2] + s1s[3]));
    atomicAdd(&ws->sum_ce_all[batch], (s2s[0] + s2s[1]) + (s2s[2] + s2s[3]));
    atomicAdd(&ws->sum_ce_pos[batch], (s3s[0] + s3s[1]) + (s3s[2] + s3s[3]));
    atomicAdd(&ws->num_pos[batch],     s4s[0] + s4s[1] + s4s[2] + s4s[3]);
  }
}

// ---------------- K2: general top-k negative selection (case 2) ----------------
// Only runs for batches where num_neg < (P - num_pos). For the bench data this
// never triggers (num_neg = P-1 >= M), so the block exits immediately.
__global__ __launch_bounds__(256) void k_select(
    const float2* __restrict__ conf, const int* __restrict__ conft,
    Ws* __restrict__ ws) {
  const int b = blockIdx.x;
  const int npos = ws->num_pos[b];
  const long long M = (long long)PP - npos;
  long long k = (long long)NEG_RATIO * npos;
  if (k > PP - 1) k = PP - 1;
  if (k >= M) return;   // case 1: sel == everything, finalize handles it
  if (k <= 0) return;   // no negatives selected

  const int tid = threadIdx.x;
  const int rowbase = b * PP;

  __shared__ unsigned hist[2048];
  __shared__ unsigned sh_prefix;
  __shared__ long long sh_kk;

  unsigned prefix = 0;
  long long kk = k;
  const int shifts[3] = {21, 10, 0};
  const int widths[3] = {11, 11, 10};

  for (int pass = 0; pass < 3; ++pass) {
    const int shift = shifts[pass], width = widths[pass];
    const unsigned mask = (1u << width) - 1u;
    for (int j = tid; j < 2048; j += 256) hist[j] = 0;
    __syncthreads();
    for (int i = tid; i < PP; i += 256) {
      const float2 c = conf[rowbase + i];
      const int t = conft[rowbase + i];
      const float score = (t > 0) ? 0.0f : ce_of(c.x, c.y, t);
      const unsigned u = __float_as_uint(score);
      const bool match = (pass == 0) || ((u >> (shift + width)) == prefix);
      if (match) atomicAdd(&hist[(u >> shift) & mask], 1u);
    }
    __syncthreads();
    if (tid == 0) {
      long long c = 0;
      int d = (int)mask;
      for (; d >= 0; --d) {
        c += hist[d];
        if (c >= kk) break;
      }
      if (d < 0) d = 0;  // safety; invariant guarantees break
      sh_prefix = (prefix << width) | (unsigned)d;
      sh_kk = kk - (c - (long long)hist[d]);
    }
    __syncthreads();
    prefix = sh_prefix;
    kk = sh_kk;
    __syncthreads();
  }

  // prefix == T bits (k-th largest score). kk = #ties to include, ascending
  // index order (stable argsort semantics).
  const unsigned Tbits = prefix;
  double local_ce = 0.0;
  __shared__ unsigned wavecnt[4];
  __shared__ long long s_rt;
  if (tid == 0) s_rt = 0;
  __syncthreads();
  const int lane = tid & 63, wave = tid >> 6;

  for (int basei = 0; basei < PP; basei += 256) {
    const int i = basei + tid;
    const float2 c = conf[rowbase + i];
    const int t = conft[rowbase + i];
    const float ce = ce_of(c.x, c.y, t);
    const float score = (t > 0) ? 0.0f : ce;
    const unsigned u = __float_as_uint(score);
    const bool gt = u > Tbits;
    const bool eq = (u == Tbits);
    const unsigned long long bal = __ballot(eq ? 1 : 0);
    if (lane == 0) wavecnt[wave] = (unsigned)__popcll(bal);
    __syncthreads();
    long long cross = s_rt;
    for (int w = 0; w < wave; ++w) cross += wavecnt[w];
    const long long myord = cross + __popcll(bal & ((1ULL << lane) - 1ULL));
    if (gt || (eq && myord < kk)) local_ce += (double)ce;
    __syncthreads();
    if (tid == 0) s_rt += (long long)wavecnt[0] + wavecnt[1] + wavecnt[2] + wavecnt[3];
    __syncthreads();
  }

#pragma unroll
  for (int off = 32; off; off >>= 1) local_ce += __shfl_down(local_ce, off);
  __shared__ double s_ce[4];
  if (lane == 0) s_ce[wave] = local_ce;
  __syncthreads();
  if (tid == 0) ws->ce_neg[b] = (float)(s_ce[0] + s_ce[1] + s_ce[2] + s_ce[3]);
}

// ---------------- K3: finalize ----------------
__global__ __launch_bounds__(64) void k_final(const Ws* __restrict__ ws,
                                              float* __restrict__ out) {
  const int tid = threadIdx.x;
  double np_d = 0.0, ce_sel = 0.0, cnt = 0.0, sl1 = 0.0;
  if (tid < BB) {
    const int npos = ws->num_pos[tid];
    const long long M = (long long)PP - npos;
    long long k = (long long)NEG_RATIO * npos;
    if (k > PP - 1) k = PP - 1;
    np_d = (double)npos;
    sl1 = (double)ws->sum_sl1[tid];
    if (k >= M) {  // case 1: sel covers every prior
      ce_sel = (double)ws->sum_ce_all[tid];
      cnt = (double)PP;
    } else {
      const long long kc = k > 0 ? k : 0;
      ce_sel = (double)ws->sum_ce_pos[tid] + (double)ws->ce_neg[tid];
      cnt = (double)(npos + kc);
    }
  }
#pragma unroll
  for (int off = 32; off; off >>= 1) {
    np_d   += __shfl_down(np_d, off);
    ce_sel += __shfl_down(ce_sel, off);
    cnt    += __shfl_down(cnt, off);
    sl1    += __shfl_down(sl1, off);
  }
  if (tid == 0) {
    const double N = np_d;
    out[0] = (float)(sl1 / (4.0 * N * N));
    out[1] = (float)(ce_sel / cnt / N);
  }
}

extern "C" void kernel_launch(void* const* d_in, const int* in_sizes, int n_in,
                              void* d_out, int out_size, void* d_ws, size_t ws_size,
                              hipStream_t stream) {
  const float4* loc   = (const float4*)d_in[0];
  const float4* conf2 = (const float4*)d_in[1];
  const float2* conf  = (const float2*)d_in[1];
  const float4* loct  = (const float4*)d_in[2];
  const int*    cnft  = (const int*)d_in[3];
  const int4*   cnft4 = (const int4*)d_in[3];
  Ws* ws = (Ws*)d_ws;

  hipMemsetAsync(d_ws, 0, sizeof(Ws), stream);
  k_main<<<dim3((BB * PP) / 1024), dim3(256), 0, stream>>>(loc, conf2, loct, cnft4, ws);
  k_select<<<dim3(BB), dim3(256), 0, stream>>>(conf, cnft, ws);
  k_final<<<dim3(1), dim3(64), 0, stream>>>(ws, (float*)d_out);
}